// Round 1
// baseline (1008.398 us; speedup 1.0000x reference)
//
#include <hip/hip_runtime.h>

#define HH 16
#define LL 2048
#define DD 64
#define BQ 128
#define BK 64
#define NQ (LL/BQ)   /* 16 */
#define NK (LL/BK)   /* 32 */
#define SCALE 0.125f

// ---------------- kernel 1: per-head k mean over L ----------------
__global__ void kmean_kernel(const float* __restrict__ k, float* __restrict__ kmean) {
    int h = blockIdx.x;
    int t = threadIdx.x;            // 256
    int d = t & 63, c = t >> 6;     // c: 0..3
    const float* kh = k + (size_t)h * LL * DD;
    float s = 0.f;
    int l0 = c * (LL/4), l1 = l0 + (LL/4);
    for (int l = l0; l < l1; ++l) s += kh[(size_t)l * DD + d];
    __shared__ float red[4][64];
    red[c][d] = s;
    __syncthreads();
    if (t < 64)
        kmean[h*DD + t] = (red[0][t] + red[1][t] + red[2][t] + red[3][t]) * (1.0f/LL);
}

// ---------------- kernel 2a: q block mean + self-similarity ----------------
__global__ void qstat_kernel(const float* __restrict__ q, const float* __restrict__ simth,
                             float* __restrict__ qm, int* __restrict__ compq) {
    int qi = blockIdx.x, h = blockIdx.y;
    int t = threadIdx.x;            // 128, one token each
    const float* row = q + ((size_t)h*LL + (size_t)qi*BQ + t) * DD;
    float x[DD]; float n2 = 0.f;
    #pragma unroll
    for (int d = 0; d < DD; d += 4) {
        float4 v4 = *(const float4*)(row + d);
        x[d]=v4.x; x[d+1]=v4.y; x[d+2]=v4.z; x[d+3]=v4.w;
        n2 += v4.x*v4.x + v4.y*v4.y + v4.z*v4.z + v4.w*v4.w;
    }
    __shared__ float xs[BQ][DD+1];
    #pragma unroll
    for (int d = 0; d < DD; ++d) xs[t][d] = x[d];
    __syncthreads();
    __shared__ float mean[DD];
    if (t < DD) {
        float s = 0.f;
        for (int r = 0; r < BQ; ++r) s += xs[r][t];
        mean[t] = s * (1.0f/BQ);
    }
    __syncthreads();
    float dot = 0.f, m2 = 0.f;
    #pragma unroll
    for (int d = 0; d < DD; ++d) { dot += x[d]*mean[d]; m2 += mean[d]*mean[d]; }
    float cs = dot / ((sqrtf(n2) + 1e-6f) * (sqrtf(m2) + 1e-6f));
    __shared__ float red[BQ];
    red[t] = cs; __syncthreads();
    for (int sft = BQ/2; sft > 0; sft >>= 1) {
        if (t < sft) red[t] += red[t + sft];
        __syncthreads();
    }
    if (t == 0) compq[h*NQ + qi] = (red[0] * (1.0f/BQ)) > simth[h] ? 1 : 0;
    if (t < DD) qm[((size_t)h*NQ + qi)*DD + t] = mean[t];
}

// ---------------- kernel 2b: k block mean + self-similarity (centered) ----------------
__global__ void kstat_kernel(const float* __restrict__ k, const float* __restrict__ kmean,
                             const float* __restrict__ simth,
                             float* __restrict__ km, int* __restrict__ compk) {
    int ki = blockIdx.x, h = blockIdx.y;
    int t = threadIdx.x;            // 64, one token each
    const float* row = k + ((size_t)h*LL + (size_t)ki*BK + t) * DD;
    const float* mu = kmean + h*DD;
    float x[DD]; float n2 = 0.f;
    #pragma unroll
    for (int d = 0; d < DD; d += 4) {
        float4 v4 = *(const float4*)(row + d);
        v4.x -= mu[d]; v4.y -= mu[d+1]; v4.z -= mu[d+2]; v4.w -= mu[d+3];
        x[d]=v4.x; x[d+1]=v4.y; x[d+2]=v4.z; x[d+3]=v4.w;
        n2 += v4.x*v4.x + v4.y*v4.y + v4.z*v4.z + v4.w*v4.w;
    }
    __shared__ float xs[BK][DD+1];
    #pragma unroll
    for (int d = 0; d < DD; ++d) xs[t][d] = x[d];
    __syncthreads();
    __shared__ float mean[DD];
    {
        float s = 0.f;
        for (int r = 0; r < BK; ++r) s += xs[r][t];
        mean[t] = s * (1.0f/BK);
    }
    __syncthreads();
    float dot = 0.f, m2 = 0.f;
    #pragma unroll
    for (int d = 0; d < DD; ++d) { dot += x[d]*mean[d]; m2 += mean[d]*mean[d]; }
    float cs = dot / ((sqrtf(n2) + 1e-6f) * (sqrtf(m2) + 1e-6f));
    __shared__ float red[BK];
    red[t] = cs; __syncthreads();
    for (int sft = BK/2; sft > 0; sft >>= 1) {
        if (t < sft) red[t] += red[t + sft];
        __syncthreads();
    }
    if (t == 0) compk[h*NK + ki] = (red[0] * (1.0f/BK)) > simth[h] ? 1 : 0;
    km[((size_t)h*NK + ki)*DD + t] = mean[t];
}

// ---------------- kernel 3: block softmax + CDF selection -> bmask ----------------
__global__ void bmask_kernel(const float* __restrict__ qm, const float* __restrict__ km,
                             const int* __restrict__ compq, const int* __restrict__ compk,
                             const float* __restrict__ cdfth, int* __restrict__ bmask) {
    int qi = blockIdx.x, h = blockIdx.y;
    int j = threadIdx.x;            // 32
    __shared__ float ssh[NK];
    __shared__ float p[NK];
    const float* qv = qm + ((size_t)h*NQ + qi)*DD;
    const float* kv = km + ((size_t)h*NK + j)*DD;
    float s = 0.f;
    for (int d = 0; d < DD; ++d) s += qv[d]*kv[d];
    ssh[j] = s * SCALE;
    __syncthreads();
    float m = ssh[0];
    for (int i = 1; i < NK; ++i) m = fmaxf(m, ssh[i]);
    float den = 0.f;
    for (int i = 0; i < NK; ++i) den += expf(ssh[i] - m);
    p[j] = expf(ssh[j] - m) / den;
    __syncthreads();
    // stable descending rank: mass of all strictly-better (or equal with lower idx) blocks
    float pj = p[j];
    float mass = 0.f;
    for (int i = 0; i < NK; ++i) {
        float pi = p[i];
        if (pi > pj || (pi == pj && i < j)) mass += pi;
    }
    int sel = (mass < cdfth[h]) ? 1 : 0;
    int keep = (sel || !(compq[h*NQ+qi] && compk[h*NK+j])) ? 1 : 0;
    bmask[((size_t)h*NQ + qi)*NK + j] = keep;
}

// ---------------- kernel 4: masked flash attention (fp32) ----------------
// One block per (qi, h): 256 threads. Thread t handles q-row (t&127); the two
// 128-thread halves (g = t>>7) split the selected k-blocks by parity, each with
// its own LDS k/v tile; partials merged via flash-combine at the end.
__global__ __launch_bounds__(256) void attn_kernel(
        const float* __restrict__ q, const float* __restrict__ k, const float* __restrict__ v,
        const float* __restrict__ kmean, const int* __restrict__ bmask,
        float* __restrict__ out) {
    constexpr int TILE = BK * DD;          // 4096 floats
    __shared__ float lds[4][TILE];         // [0..1]: ks per group, [2..3]: vs per group (64 KB)
    int qi = blockIdx.x, h = blockIdx.y;
    int t = threadIdx.x;
    int r = t & (BQ - 1);
    int g = t >> 7;
    float* ksg = lds[g];
    float* vsg = lds[2 + g];

    // selected-block bitmask (uniform across all threads)
    unsigned msk = 0;
    {
        const int* bm = bmask + ((size_t)h*NQ + qi)*NK;
        for (int j = 0; j < NK; ++j) msk |= (bm[j] ? 1u : 0u) << j;
    }

    const float* qrow = q + ((size_t)h*LL + (size_t)qi*BQ + r) * DD;
    float qr[DD];
    #pragma unroll
    for (int d = 0; d < DD; d += 4) {
        float4 v4 = *(const float4*)(qrow + d);
        qr[d]=v4.x; qr[d+1]=v4.y; qr[d+2]=v4.z; qr[d+3]=v4.w;
    }
    float acc[DD];
    #pragma unroll
    for (int d = 0; d < DD; ++d) acc[d] = 0.f;
    float mrun = -1e30f, lrun = 0.f;

    const float* kh = k + (size_t)h*LL*DD;
    const float* vh = v + (size_t)h*LL*DD;
    const float* mu = kmean + h*DD;

    while (msk) {
        int j0 = __ffs(msk) - 1; msk &= msk - 1;
        int j1 = -1;
        if (msk) { j1 = __ffs(msk) - 1; msk &= msk - 1; }
        int jg = g ? j1 : j0;

        __syncthreads();   // previous tile fully consumed before overwrite
        if (jg >= 0) {
            const float4* ksrc = (const float4*)(kh + (size_t)jg*TILE);
            const float4* vsrc = (const float4*)(vh + (size_t)jg*TILE);
            float4* kdst = (float4*)ksg;
            float4* vdst = (float4*)vsg;
            int tl = t & 127;
            #pragma unroll
            for (int i = 0; i < 8; ++i) {
                int f = tl + i*128;            // 0..1023 float4 index
                float4 kv = ksrc[f];
                int dd4 = (f & 15) * 4;
                kv.x -= mu[dd4]; kv.y -= mu[dd4+1]; kv.z -= mu[dd4+2]; kv.w -= mu[dd4+3];
                kdst[f] = kv;
                vdst[f] = vsrc[f];
            }
        }
        __syncthreads();   // tile visible to the whole group
        if (jg >= 0) {
            #pragma unroll 1
            for (int c = 0; c < BK/16; ++c) {
                float s16[16];
                #pragma unroll
                for (int kk = 0; kk < 16; ++kk) {
                    const float4* krow = (const float4*)(ksg + (c*16 + kk)*DD);
                    float a = 0.f;
                    #pragma unroll
                    for (int d4 = 0; d4 < DD/4; ++d4) {
                        float4 kv = krow[d4];
                        a += qr[d4*4]*kv.x + qr[d4*4+1]*kv.y + qr[d4*4+2]*kv.z + qr[d4*4+3]*kv.w;
                    }
                    s16[kk] = a * SCALE;
                }
                float mb = s16[0];
                #pragma unroll
                for (int kk = 1; kk < 16; ++kk) mb = fmaxf(mb, s16[kk]);
                float mnew = fmaxf(mrun, mb);
                float alpha = __expf(mrun - mnew);
                lrun *= alpha;
                #pragma unroll
                for (int d = 0; d < DD; ++d) acc[d] *= alpha;
                #pragma unroll
                for (int kk = 0; kk < 16; ++kk) {
                    float pr = __expf(s16[kk] - mnew);
                    lrun += pr;
                    const float4* vrow = (const float4*)(vsg + (c*16 + kk)*DD);
                    #pragma unroll
                    for (int d4 = 0; d4 < DD/4; ++d4) {
                        float4 vv = vrow[d4];
                        acc[d4*4]   += pr*vv.x;
                        acc[d4*4+1] += pr*vv.y;
                        acc[d4*4+2] += pr*vv.z;
                        acc[d4*4+3] += pr*vv.w;
                    }
                }
                mrun = mnew;
            }
        }
    }

    // merge the two groups' partial (m, l, acc) per row
    __syncthreads();
    float* accbuf = lds[0];                 // 8192 floats (spans lds[0..1])
    float* mbuf = lds[2];
    float* lbuf = lds[2] + BQ;
    if (g == 1) {
        mbuf[r] = mrun; lbuf[r] = lrun;
        #pragma unroll
        for (int d = 0; d < DD; ++d) accbuf[r*DD + d] = acc[d];
    }
    __syncthreads();
    if (g == 0) {
        float m1 = mbuf[r], l1 = lbuf[r];
        float mf = fmaxf(mrun, m1);
        float a0 = __expf(mrun - mf), a1 = __expf(m1 - mf);
        float lf = lrun*a0 + l1*a1;
        float inv = 1.0f / lf;
        float* orow = out + ((size_t)h*LL + (size_t)qi*BQ + r) * DD;
        #pragma unroll
        for (int d = 0; d < DD; d += 4) {
            float4 o;
            o.x = (acc[d  ]*a0 + accbuf[r*DD + d  ]*a1) * inv;
            o.y = (acc[d+1]*a0 + accbuf[r*DD + d+1]*a1) * inv;
            o.z = (acc[d+2]*a0 + accbuf[r*DD + d+2]*a1) * inv;
            o.w = (acc[d+3]*a0 + accbuf[r*DD + d+3]*a1) * inv;
            *(float4*)(orow + d) = o;
        }
    }
}

extern "C" void kernel_launch(void* const* d_in, const int* in_sizes, int n_in,
                              void* d_out, int out_size, void* d_ws, size_t ws_size,
                              hipStream_t stream) {
    const float* q     = (const float*)d_in[0];
    const float* k     = (const float*)d_in[1];
    const float* v     = (const float*)d_in[2];
    const float* simth = (const float*)d_in[3];
    const float* cdfth = (const float*)d_in[4];
    float* out = (float*)d_out;

    float* ws    = (float*)d_ws;
    float* kmean = ws;                       // 16*64
    float* qm    = kmean + HH*DD;            // 16*16*64
    float* km    = qm + HH*NQ*DD;            // 16*32*64
    int*   compq = (int*)(km + HH*NK*DD);    // 256
    int*   compk = compq + HH*NQ;            // 512
    int*   bmk   = compk + HH*NK;            // 16*16*32

    kmean_kernel<<<dim3(HH), 256, 0, stream>>>(k, kmean);
    qstat_kernel<<<dim3(NQ, HH), BQ, 0, stream>>>(q, simth, qm, compq);
    kstat_kernel<<<dim3(NK, HH), BK, 0, stream>>>(k, kmean, simth, km, compk);
    bmask_kernel<<<dim3(NQ, HH), NK, 0, stream>>>(qm, km, compq, compk, cdfth, bmk);
    attn_kernel<<<dim3(NQ, HH), 2*BQ, 0, stream>>>(q, k, v, kmean, bmk, out);
}

// Round 2
// 113.058 us; speedup vs baseline: 8.9193x; 8.9193x over previous
//
#include <hip/hip_runtime.h>

#define HH 16
#define LL 2048
#define DD 64
#define BQ 128
#define BK 64
#define NQ (LL/BQ)   /* 16 */
#define NK (LL/BK)   /* 32 */
#define SCALE 0.125f

typedef __attribute__((ext_vector_type(8))) short s8v;   // 8 bf16 (4 VGPR)
typedef __attribute__((ext_vector_type(4))) float f4v;   // 4 fp32 acc

static __device__ __forceinline__ ushort f2bf(float x) {
    unsigned u = __float_as_uint(x);
    u += 0x7fff + ((u >> 16) & 1);       // round-to-nearest-even
    return (ushort)(u >> 16);
}

// ---------------- kernel 1: per-head k mean over L ----------------
__global__ void kmean_kernel(const float* __restrict__ k, float* __restrict__ kmean) {
    int h = blockIdx.x;
    int t = threadIdx.x;            // 256
    int d = t & 63, c = t >> 6;     // c: 0..3
    const float* kh = k + (size_t)h * LL * DD;
    float s = 0.f;
    int l0 = c * (LL/4), l1 = l0 + (LL/4);
    for (int l = l0; l < l1; ++l) s += kh[(size_t)l * DD + d];
    __shared__ float red[4][64];
    red[c][d] = s;
    __syncthreads();
    if (t < 64)
        kmean[h*DD + t] = (red[0][t] + red[1][t] + red[2][t] + red[3][t]) * (1.0f/LL);
}

// ---------------- kernel 2a: q block mean + self-similarity ----------------
__global__ void qstat_kernel(const float* __restrict__ q, const float* __restrict__ simth,
                             float* __restrict__ qm, int* __restrict__ compq) {
    int qi = blockIdx.x, h = blockIdx.y;
    int t = threadIdx.x;            // 128, one token each
    const float* row = q + ((size_t)h*LL + (size_t)qi*BQ + t) * DD;
    float x[DD]; float n2 = 0.f;
    #pragma unroll
    for (int d = 0; d < DD; d += 4) {
        float4 v4 = *(const float4*)(row + d);
        x[d]=v4.x; x[d+1]=v4.y; x[d+2]=v4.z; x[d+3]=v4.w;
        n2 += v4.x*v4.x + v4.y*v4.y + v4.z*v4.z + v4.w*v4.w;
    }
    __shared__ float xs[BQ][DD+1];
    #pragma unroll
    for (int d = 0; d < DD; ++d) xs[t][d] = x[d];
    __syncthreads();
    __shared__ float mean[DD];
    if (t < DD) {
        float s = 0.f;
        for (int r = 0; r < BQ; ++r) s += xs[r][t];
        mean[t] = s * (1.0f/BQ);
    }
    __syncthreads();
    float dot = 0.f, m2 = 0.f;
    #pragma unroll
    for (int d = 0; d < DD; ++d) { dot += x[d]*mean[d]; m2 += mean[d]*mean[d]; }
    float cs = dot / ((sqrtf(n2) + 1e-6f) * (sqrtf(m2) + 1e-6f));
    __shared__ float red[BQ];
    red[t] = cs; __syncthreads();
    for (int sft = BQ/2; sft > 0; sft >>= 1) {
        if (t < sft) red[t] += red[t + sft];
        __syncthreads();
    }
    if (t == 0) compq[h*NQ + qi] = (red[0] * (1.0f/BQ)) > simth[h] ? 1 : 0;
    if (t < DD) qm[((size_t)h*NQ + qi)*DD + t] = mean[t];
}

// ---------------- kernel 2b: k block mean + self-similarity (centered) ----------------
__global__ void kstat_kernel(const float* __restrict__ k, const float* __restrict__ kmean,
                             const float* __restrict__ simth,
                             float* __restrict__ km, int* __restrict__ compk) {
    int ki = blockIdx.x, h = blockIdx.y;
    int t = threadIdx.x;            // 64, one token each
    const float* row = k + ((size_t)h*LL + (size_t)ki*BK + t) * DD;
    const float* mu = kmean + h*DD;
    float x[DD]; float n2 = 0.f;
    #pragma unroll
    for (int d = 0; d < DD; d += 4) {
        float4 v4 = *(const float4*)(row + d);
        v4.x -= mu[d]; v4.y -= mu[d+1]; v4.z -= mu[d+2]; v4.w -= mu[d+3];
        x[d]=v4.x; x[d+1]=v4.y; x[d+2]=v4.z; x[d+3]=v4.w;
        n2 += v4.x*v4.x + v4.y*v4.y + v4.z*v4.z + v4.w*v4.w;
    }
    __shared__ float xs[BK][DD+1];
    #pragma unroll
    for (int d = 0; d < DD; ++d) xs[t][d] = x[d];
    __syncthreads();
    __shared__ float mean[DD];
    {
        float s = 0.f;
        for (int r = 0; r < BK; ++r) s += xs[r][t];
        mean[t] = s * (1.0f/BK);
    }
    __syncthreads();
    float dot = 0.f, m2 = 0.f;
    #pragma unroll
    for (int d = 0; d < DD; ++d) { dot += x[d]*mean[d]; m2 += mean[d]*mean[d]; }
    float cs = dot / ((sqrtf(n2) + 1e-6f) * (sqrtf(m2) + 1e-6f));
    __shared__ float red[BK];
    red[t] = cs; __syncthreads();
    for (int sft = BK/2; sft > 0; sft >>= 1) {
        if (t < sft) red[t] += red[t + sft];
        __syncthreads();
    }
    if (t == 0) compk[h*NK + ki] = (red[0] * (1.0f/BK)) > simth[h] ? 1 : 0;
    km[((size_t)h*NK + ki)*DD + t] = mean[t];
}

// ---------------- kernel 3: block softmax + CDF selection -> packed bitmask ----------------
__global__ void bmask_kernel(const float* __restrict__ qm, const float* __restrict__ km,
                             const int* __restrict__ compq, const int* __restrict__ compk,
                             const float* __restrict__ cdfth, unsigned* __restrict__ bmaskbits) {
    int qi = blockIdx.x, h = blockIdx.y;
    int j = threadIdx.x;            // 32 (lanes 0..31 of one wave)
    __shared__ float ssh[NK];
    __shared__ float p[NK];
    const float* qv = qm + ((size_t)h*NQ + qi)*DD;
    const float* kv = km + ((size_t)h*NK + j)*DD;
    float s = 0.f;
    for (int d = 0; d < DD; ++d) s += qv[d]*kv[d];
    ssh[j] = s * SCALE;
    __syncthreads();
    float m = ssh[0];
    for (int i = 1; i < NK; ++i) m = fmaxf(m, ssh[i]);
    float den = 0.f;
    for (int i = 0; i < NK; ++i) den += expf(ssh[i] - m);
    p[j] = expf(ssh[j] - m) / den;
    __syncthreads();
    // stable descending rank: mass of all strictly-better (or equal with lower idx) blocks
    float pj = p[j];
    float mass = 0.f;
    for (int i = 0; i < NK; ++i) {
        float pi = p[i];
        if (pi > pj || (pi == pj && i < j)) mass += pi;
    }
    int sel = (mass < cdfth[h]) ? 1 : 0;
    int keep = (sel || !(compq[h*NQ+qi] && compk[h*NK+j])) ? 1 : 0;
    unsigned long long bal = __ballot(keep);
    if (j == 0) bmaskbits[h*NQ + qi] = (unsigned)bal;
}

// ---------------- kernel 3.5: bf16 conversion pre-pass ----------------
// qb = bf16(q * SCALE), kb = bf16(k - kmean), vTb = bf16(v)^T per head [DD][LL]
__global__ __launch_bounds__(256) void convert_kernel(
        const float* __restrict__ q, const float* __restrict__ k, const float* __restrict__ v,
        const float* __restrict__ kmean,
        ushort* __restrict__ qb, ushort* __restrict__ kb, ushort* __restrict__ vTb) {
    int c = blockIdx.x;   // token chunk of 64 (0..31)
    int h = blockIdx.y;
    int t = threadIdx.x;  // 256
    size_t base = ((size_t)h*LL + (size_t)c*64) * DD;   // 4096 elements
    const float* mu = kmean + h*DD;
    __shared__ float tile[64][65];
    #pragma unroll
    for (int i = 0; i < 4; ++i) {
        int f = t + i*256;            // float4 index 0..1023
        int d4 = (f & 15) * 4;
        int row = f >> 4;
        float4 qv = ((const float4*)(q + base))[f];
        ushort4 qo;
        qo.x = f2bf(qv.x * SCALE); qo.y = f2bf(qv.y * SCALE);
        qo.z = f2bf(qv.z * SCALE); qo.w = f2bf(qv.w * SCALE);
        ((ushort4*)(qb + base))[f] = qo;
        float4 kv = ((const float4*)(k + base))[f];
        ushort4 ko;
        ko.x = f2bf(kv.x - mu[d4]);   ko.y = f2bf(kv.y - mu[d4+1]);
        ko.z = f2bf(kv.z - mu[d4+2]); ko.w = f2bf(kv.w - mu[d4+3]);
        ((ushort4*)(kb + base))[f] = ko;
        float4 vv = ((const float4*)(v + base))[f];
        tile[row][d4] = vv.x; tile[row][d4+1] = vv.y;
        tile[row][d4+2] = vv.z; tile[row][d4+3] = vv.w;
    }
    __syncthreads();
    int tok = t & 63;
    int dbase = (t >> 6) * 16;
    #pragma unroll
    for (int i = 0; i < 16; ++i) {
        int d = dbase + i;
        vTb[((size_t)h*DD + d)*LL + (size_t)c*64 + tok] = f2bf(tile[tok][d]);
    }
}

// ---------------- kernel 4: masked flash attention, MFMA bf16 ----------------
// One wave (64 threads) per 32 q-rows. grid = (NQ*4, HH). No barriers.
// mfma_f32_16x16x32_bf16 layouts:
//   A: lane l holds A[l&15][(l>>4)*8 + j]   (16B contiguous along K)
//   B: lane l holds B[(l>>4)*8 + j][l&15]
//   C/D: lane l, reg r holds D[(l>>4)*4 + r][l&15]   (m89-verified)
__global__ __launch_bounds__(64) void attn_kernel(
        const ushort* __restrict__ qb, const ushort* __restrict__ kb,
        const ushort* __restrict__ vTb, const unsigned* __restrict__ bmaskbits,
        float* __restrict__ out) {
    int h  = blockIdx.y;
    int qi = blockIdx.x >> 2;
    int w  = blockIdx.x & 3;
    int l  = threadIdx.x;
    int lo = l & 15, hi = l >> 4;
    int r0 = qi*BQ + w*32;

    __shared__ __align__(16) ushort plds[32][80];   // padded: b128 read-back conflict-free

    unsigned msk = bmaskbits[h*NQ + qi];

    const ushort* qh = qb  + (size_t)h*LL*DD;
    const ushort* kh = kb  + (size_t)h*LL*DD;
    const ushort* vh = vTb + (size_t)h*DD*LL;

    // Q A-frags: invariant over k-blocks
    s8v qa[2][2];
    #pragma unroll
    for (int mi = 0; mi < 2; ++mi)
        #pragma unroll
        for (int kk = 0; kk < 2; ++kk)
            qa[mi][kk] = *(const s8v*)(qh + (size_t)(r0 + mi*16 + lo)*DD + kk*32 + hi*8);

    f4v O[2][4];
    float mrun[2][4], lrun[2][4];
    #pragma unroll
    for (int mi = 0; mi < 2; ++mi)
        #pragma unroll
        for (int r = 0; r < 4; ++r) {
            mrun[mi][r] = -1e30f; lrun[mi][r] = 0.f;
        }
    #pragma unroll
    for (int mi = 0; mi < 2; ++mi)
        #pragma unroll
        for (int nd = 0; nd < 4; ++nd)
            O[mi][nd] = (f4v){0.f, 0.f, 0.f, 0.f};

    while (msk) {
        int j = __ffs(msk) - 1; msk &= msk - 1;
        const ushort* kbj = kh + (size_t)j*BK*DD;
        const ushort* vbj = vh + (size_t)j*BK;      // column offset within vT row

        // V B-frags up front: latency hides under QK^T + softmax
        s8v vf[4][2];
        #pragma unroll
        for (int nd = 0; nd < 4; ++nd)
            #pragma unroll
            for (int kk = 0; kk < 2; ++kk)
                vf[nd][kk] = *(const s8v*)(vbj + (size_t)(nd*16 + lo)*LL + kk*32 + hi*8);

        // QK^T: S[mi][ni] = Q(32x64) . K^T(64x64)
        f4v S[2][4];
        #pragma unroll
        for (int mi = 0; mi < 2; ++mi)
            #pragma unroll
            for (int ni = 0; ni < 4; ++ni)
                S[mi][ni] = (f4v){0.f, 0.f, 0.f, 0.f};
        #pragma unroll
        for (int kk = 0; kk < 2; ++kk)
            #pragma unroll
            for (int ni = 0; ni < 4; ++ni) {
                s8v kf = *(const s8v*)(kbj + (size_t)(ni*16 + lo)*DD + kk*32 + hi*8);
                S[0][ni] = __builtin_amdgcn_mfma_f32_16x16x32_bf16(qa[0][kk], kf, S[0][ni], 0, 0, 0);
                S[1][ni] = __builtin_amdgcn_mfma_f32_16x16x32_bf16(qa[1][kk], kf, S[1][ni], 0, 0, 0);
            }

        // online softmax (row = (hi)*4+r within 16-tile; reduce over ni regs + 16-lane group)
        #pragma unroll
        for (int mi = 0; mi < 2; ++mi) {
            float bm[4];
            #pragma unroll
            for (int r = 0; r < 4; ++r)
                bm[r] = fmaxf(fmaxf(S[mi][0][r], S[mi][1][r]), fmaxf(S[mi][2][r], S[mi][3][r]));
            #pragma unroll
            for (int xm = 1; xm <= 8; xm <<= 1)
                #pragma unroll
                for (int r = 0; r < 4; ++r)
                    bm[r] = fmaxf(bm[r], __shfl_xor(bm[r], xm));
            #pragma unroll
            for (int r = 0; r < 4; ++r) {
                float mn = fmaxf(mrun[mi][r], bm[r]);
                float al = __expf(mrun[mi][r] - mn);
                mrun[mi][r] = mn;
                lrun[mi][r] *= al;
                #pragma unroll
                for (int nd = 0; nd < 4; ++nd) O[mi][nd][r] *= al;
            }
            #pragma unroll
            for (int ni = 0; ni < 4; ++ni)
                #pragma unroll
                for (int r = 0; r < 4; ++r) {
                    float p = __expf(S[mi][ni][r] - mrun[mi][r]);
                    lrun[mi][r] += p;
                    plds[mi*16 + hi*4 + r][ni*16 + lo] = f2bf(p);
                }
        }

        // PV: O += P(32x64) . V(64x64); P read back from LDS in A-layout
        #pragma unroll
        for (int kk = 0; kk < 2; ++kk) {
            s8v pa0 = *(const s8v*)&plds[lo][kk*32 + hi*8];
            s8v pa1 = *(const s8v*)&plds[16 + lo][kk*32 + hi*8];
            #pragma unroll
            for (int nd = 0; nd < 4; ++nd) {
                O[0][nd] = __builtin_amdgcn_mfma_f32_16x16x32_bf16(pa0, vf[nd][kk], O[0][nd], 0, 0, 0);
                O[1][nd] = __builtin_amdgcn_mfma_f32_16x16x32_bf16(pa1, vf[nd][kk], O[1][nd], 0, 0, 0);
            }
        }
    }

    // epilogue: finish row-sums across the 16-lane group, normalize, store
    #pragma unroll
    for (int mi = 0; mi < 2; ++mi)
        #pragma unroll
        for (int r = 0; r < 4; ++r) {
            float lsum = lrun[mi][r];
            #pragma unroll
            for (int xm = 1; xm <= 8; xm <<= 1) lsum += __shfl_xor(lsum, xm);
            float inv = 1.0f / lsum;
            int row = r0 + mi*16 + hi*4 + r;
            float* orow = out + ((size_t)h*LL + row)*DD;
            #pragma unroll
            for (int nd = 0; nd < 4; ++nd)
                orow[nd*16 + lo] = O[mi][nd][r] * inv;
        }
}

extern "C" void kernel_launch(void* const* d_in, const int* in_sizes, int n_in,
                              void* d_out, int out_size, void* d_ws, size_t ws_size,
                              hipStream_t stream) {
    const float* q     = (const float*)d_in[0];
    const float* k     = (const float*)d_in[1];
    const float* v     = (const float*)d_in[2];
    const float* simth = (const float*)d_in[3];
    const float* cdfth = (const float*)d_in[4];
    float* out = (float*)d_out;

    float* ws    = (float*)d_ws;
    float* kmean = ws;                       // 16*64
    float* qm    = kmean + HH*DD;            // 16*16*64
    float* km    = qm + HH*NQ*DD;            // 16*32*64
    int*   compq = (int*)(km + HH*NK*DD);    // 256
    int*   compk = compq + HH*NQ;            // 512
    unsigned* bmb = (unsigned*)(compk + HH*NK);  // 256
    size_t off = (size_t)((char*)(bmb + HH*NQ) - (char*)d_ws);
    off = (off + 15) & ~(size_t)15;
    ushort* qbuf = (ushort*)((char*)d_ws + off);
    ushort* kbuf = qbuf + (size_t)HH*LL*DD;
    ushort* vTb  = kbuf + (size_t)HH*LL*DD;

    kmean_kernel<<<dim3(HH), 256, 0, stream>>>(k, kmean);
    qstat_kernel<<<dim3(NQ, HH), BQ, 0, stream>>>(q, simth, qm, compq);
    kstat_kernel<<<dim3(NK, HH), BK, 0, stream>>>(k, kmean, simth, km, compk);
    convert_kernel<<<dim3(NK, HH), 256, 0, stream>>>(q, k, v, kmean, qbuf, kbuf, vTb);
    bmask_kernel<<<dim3(NQ, HH), NK, 0, stream>>>(qm, km, compq, compk, cdfth, bmb);
    attn_kernel<<<dim3(NQ*4, HH), 64, 0, stream>>>(qbuf, kbuf, vTb, bmb, out);
}